// Round 13
// baseline (393.621 us; speedup 1.0000x reference)
//
#include <hip/hip_runtime.h>
#include <hip/hip_bf16.h>
#include <stdint.h>

// Problem constants (SymNetDP): B=64, S=4096, NGB=13, NG=48, DIM=3, NCH={8,8,1}
#define BATCH 64
#define SITES 4096
#define NGB 13
#define NGRP 48
#define SDIM 3

typedef __bf16 bf16x8 __attribute__((ext_vector_type(8)));
typedef float  f32x4  __attribute__((ext_vector_type(4)));

// ---------------------------------------------------------------------------
// Workspace (floats):
//   Avc @0 (64) | U (bf16 weights) @64..67648
//     W0H[384][32] | W0L | W1H[384][128] | W1L | W2H[48][128] | W2L (pads 0)
//   Ah0 @67648  Al0 @1116224  Ah1 @2164800  Al1 @3213376   ((B,S,8) bf16 each)
//   C   @4261952 [3][4096] | PART @4274240 [4096][3]
// K-packing (NCIN=8): k = j*8 + c. Intermediates PRE-SPLIT hi/lo bf16,
// written coalesced (16B/site lines), consumed via global_load_lds DMA.
// ---------------------------------------------------------------------------
#define OFF_AVC  0
#define OFF_U    64
#define OFF_AH0  67648
#define OFF_AL0  1116224
#define OFF_AH1  2164800
#define OFF_AL1  3213376
#define OFF_C    4261952
#define OFF_PART 4274240
#define UW0H 0
#define UW0L 12288
#define UW1H 24576
#define UW1L 73728
#define UW2H 122880
#define UW2L 129024

__device__ __forceinline__ float softplus_f(float h) {
    return fmaxf(h, 0.f) + __logf(1.f + __expf(-fabsf(h)));
}

// 16B global -> LDS DMA (dest must be uniform base + lane*16)
__device__ __forceinline__ void gl_lds16(const void* g, void* l) {
    __builtin_amdgcn_global_load_lds(
        (const __attribute__((address_space(1))) uint32_t*)g,
        (__attribute__((address_space(3))) uint32_t*)l, 16, 0, 0);
}

// ---------------------------------------------------------------------------
// Precompute: rotated weights hi/lo, [row=o*48+g][KPAD], pads ZERO (no bias
// folding); Avc (atomics, zeroed by memset).
// ---------------------------------------------------------------------------
__global__ __launch_bounds__(256) void precompute_kernel(
    const float* __restrict__ Psi0, const float* __restrict__ Psi1,
    const float* __restrict__ Psi2, const float* __restrict__ wtVC,
    const float* __restrict__ gdiags, const int* __restrict__ perms,
    float* __restrict__ ws)
{
    float*  Avc = ws + OFF_AVC;
    __bf16* U   = (__bf16*)(ws + OFF_U);
    int t = blockIdx.x * 256 + threadIdx.x;
    if (t < 12288) {                       // W0: [384][32], k=j
        int k = t & 31, row = t >> 5;
        int o = row / NGRP, g = row - o * NGRP;
        float w = (k < NGB) ? Psi0[o * NGB + perms[g * NGB + k]] : 0.f;
        __bf16 hi = (__bf16)w;
        U[UW0H + t] = hi;
        U[UW0L + t] = (__bf16)(w - (float)hi);
    } else if (t < 61440) {                // W1: [384][128], k=j*8+c
        int u = t - 12288;
        int k = u & 127, row = u >> 7;
        int o = row / NGRP, g = row - o * NGRP;
        float w = 0.f;
        if (k < 104) { int j = k >> 3, c = k & 7;
                       w = Psi1[(o * 8 + c) * NGB + perms[g * NGB + j]]; }
        __bf16 hi = (__bf16)w;
        U[UW1H + u] = hi;
        U[UW1L + u] = (__bf16)(w - (float)hi);
    } else if (t < 67584) {                // W2: [48][128], k=j*8+c
        int u = t - 61440;
        int k = u & 127, g = u >> 7;
        float w = 0.f;
        if (k < 104) { int j = k >> 3, c = k & 7;
                       w = Psi2[c * NGB + perms[g * NGB + j]]; }
        __bf16 hi = (__bf16)w;
        U[UW2H + u] = hi;
        U[UW2L + u] = (__bf16)(w - (float)hi);
    } else if (t < 67584 + 39 * NGRP) {    // Avc
        int t2 = t - 67584;
        int g = t2 % NGRP, u = t2 / NGRP;
        int d = u / NGB, n = u % NGB;
        const int row = g * SDIM + d;
        float s = 0.f;
        for (int k = 0; k < NGRP * SDIM; k++) {
            int g2 = k / SDIM, d2 = k - g2 * SDIM;
            float p = wtVC[d2 * NGB + perms[g2 * NGB + n]];
            s = fmaf(gdiags[row * (NGRP * SDIM) + k], p, s);
        }
        atomicAdd(&Avc[u], s * (1.f / 48.f));
    }
}

// C[d][t] = sum_{(n,s): NN[n,s]=t} Avc[d,n] * sw[shell[s]]
__global__ __launch_bounds__(256) void precompute_C(
    const int* __restrict__ NN, const int* __restrict__ s2sh,
    const float* __restrict__ sw, const float* __restrict__ ws_avc,
    float* __restrict__ C)
{
    int e = blockIdx.x * 256 + threadIdx.x;
    if (e < NGB * SITES) {
        int n = e >> 12, s = e & (SITES - 1);
        int t = NN[n * SITES + s];
        float w = sw[s2sh[s]];
        atomicAdd(&C[t],             ws_avc[n] * w);
        atomicAdd(&C[SITES + t],     ws_avc[NGB + n] * w);
        atomicAdd(&C[2 * SITES + t], ws_avc[2 * NGB + n] * w);
    }
}

// ---------------------------------------------------------------------------
// Shared epilogue: transpose (o,col)->LDS, then 64 lanes write coalesced
// 16B hi/lo lines to Ah/Al[(b*S+s0+col)*8].
// ---------------------------------------------------------------------------
__device__ __forceinline__ void store_split8(
    float* tr, int tid, size_t base8, __bf16* OutH, __bf16* OutL)
{
    __syncthreads();
    if (tid < 64) {
        bf16x8 hv, lv;
#pragma unroll
        for (int c = 0; c < 8; c++) {
            float v = tr[tid * 8 + c];
            __bf16 hi = (__bf16)v;
            hv[c] = hi;
            lv[c] = (__bf16)(v - (float)hi);
        }
        *(bf16x8*)(OutH + base8 + (size_t)tid * 8) = hv;
        *(bf16x8*)(OutL + base8 + (size_t)tid * 8) = lv;
    }
}

// ---------------------------------------------------------------------------
// Layer 0: f32 input (B,S), LDS-staged (R9 style), output pre-split Ah0/Al0.
// ---------------------------------------------------------------------------
__global__ __launch_bounds__(512) void layer0_mfma(
    const float* __restrict__ prev, const __bf16* __restrict__ Wh,
    const __bf16* __restrict__ Wl, const float* __restrict__ bias,
    const int* __restrict__ NN, __bf16* __restrict__ OutH,
    __bf16* __restrict__ OutL)
{
    constexpr int CT = 64, KSTR = 40;
    __shared__ __align__(16) __bf16 xh[CT * KSTR];
    __shared__ __align__(16) __bf16 xl[CT * KSTR];

    const int tid  = threadIdx.x;
    const int wave = tid >> 6, lane = tid & 63;
    const int m16  = lane & 15, quad = lane >> 4;
    const int b    = blockIdx.x >> 6;
    const int s0   = (blockIdx.x & 63) << 6;
    const size_t bS = (size_t)b * SITES;

    for (int site = tid; site < NGB * CT; site += 512) {
        int j = site / CT, col = site % CT;
        float v = prev[bS + NN[j * SITES + s0 + col]];
        __bf16 hi = (__bf16)v;
        xh[col * KSTR + j] = hi;
        xl[col * KSTR + j] = (__bf16)(v - (float)hi);
    }
    for (int e = tid; e < CT * 19; e += 512) {       // k in [13,32) zero
        int col = e / 19, p = e % 19;
        xh[col * KSTR + NGB + p] = (__bf16)0.f;
        xl[col * KSTR + NGB + p] = (__bf16)0.f;
    }
    __syncthreads();

    f32x4 acc[3][4];
#pragma unroll
    for (int mt = 0; mt < 3; mt++)
#pragma unroll
        for (int nt = 0; nt < 4; nt++) acc[mt][nt] = (f32x4){0.f, 0.f, 0.f, 0.f};

    {
        const int koff = quad * 8;
        bf16x8 ah[3], al[3], bh[4], bl[4];
#pragma unroll
        for (int mt = 0; mt < 3; mt++) {
            int row = (wave * 3 + mt) * 16 + m16;
            ah[mt] = *(const bf16x8*)(Wh + (size_t)row * 32 + koff);
            al[mt] = *(const bf16x8*)(Wl + (size_t)row * 32 + koff);
        }
#pragma unroll
        for (int nt = 0; nt < 4; nt++) {
            int cb = (nt * 16 + m16) * KSTR + koff;
            bh[nt] = *(const bf16x8*)(xh + cb);
            bl[nt] = *(const bf16x8*)(xl + cb);
        }
#pragma unroll
        for (int mt = 0; mt < 3; mt++)
#pragma unroll
            for (int nt = 0; nt < 4; nt++) {
                acc[mt][nt] = __builtin_amdgcn_mfma_f32_16x16x32_bf16(ah[mt], bh[nt], acc[mt][nt], 0, 0, 0);
                acc[mt][nt] = __builtin_amdgcn_mfma_f32_16x16x32_bf16(al[mt], bh[nt], acc[mt][nt], 0, 0, 0);
                acc[mt][nt] = __builtin_amdgcn_mfma_f32_16x16x32_bf16(ah[mt], bl[nt], acc[mt][nt], 0, 0, 0);
            }
    }

    __syncthreads();                       // LDS reads done; reuse as tr
    float* tr = (float*)xh;                // [64 col][8 o] f32
    const float bo = bias[wave];
#pragma unroll
    for (int nt = 0; nt < 4; nt++) {
        float s = 0.f;
#pragma unroll
        for (int mt = 0; mt < 3; mt++)
#pragma unroll
            for (int r = 0; r < 4; r++) s += softplus_f(acc[mt][nt][r] + bo);
        s += __shfl_xor(s, 16);
        s += __shfl_xor(s, 32);
        if (quad == 0) tr[(nt * 16 + m16) * 8 + wave] = s * (1.f / 48.f);
    }
    store_split8(tr, tid, (bS + s0) * 8, OutH, OutL);
}

// ---------------------------------------------------------------------------
// Layer 1: pre-split input via global_load_lds DMA; output pre-split Ah1/Al1.
// LDS unit u = col*13+j holds site (col,j)'s 8 channels (16B). Units 832..839
// zeroed (kt=3 bleed safety: bleed reads are finite x zero-weight = 0).
// ---------------------------------------------------------------------------
__global__ __launch_bounds__(512) void layer1_mfma(
    const __bf16* __restrict__ Ah, const __bf16* __restrict__ Al,
    const __bf16* __restrict__ Wh, const __bf16* __restrict__ Wl,
    const float* __restrict__ bias, const int* __restrict__ NN,
    __bf16* __restrict__ OutH, __bf16* __restrict__ OutL)
{
    constexpr int CT = 64, KPAD = 128, NU = NGB * CT;   // 832 units
    __shared__ __align__(16) __bf16 xh[840 * 8];
    __shared__ __align__(16) __bf16 xl[840 * 8];

    const int tid  = threadIdx.x;
    const int wave = tid >> 6, lane = tid & 63;
    const int m16  = lane & 15, quad = lane >> 4;
    const int b    = blockIdx.x >> 6;
    const int s0   = (blockIdx.x & 63) << 6;
    const size_t bS = (size_t)b * SITES;

    // DMA staging: dest = base + u*16, u in lane order -> HW-legal
#pragma unroll
    for (int it = 0; it < 2; it++) {
        int u = tid + it * 512;
        if (u < NU) {
            int col = u / NGB, j = u - col * NGB;
            size_t g8 = (bS + NN[j * SITES + s0 + col]) * 8;
            gl_lds16(Ah + g8, xh + (size_t)u * 8);
            gl_lds16(Al + g8, xl + (size_t)u * 8);
        }
    }
    if (tid < 8) {                          // zero tail units 832..839
        bf16x8 z = {};
        *(bf16x8*)(xh + (NU + tid) * 8) = z;
        *(bf16x8*)(xl + (NU + tid) * 8) = z;
    }
    __syncthreads();

    f32x4 acc[3][4];
#pragma unroll
    for (int mt = 0; mt < 3; mt++)
#pragma unroll
        for (int nt = 0; nt < 4; nt++) acc[mt][nt] = (f32x4){0.f, 0.f, 0.f, 0.f};

#pragma unroll
    for (int kt = 0; kt < 4; kt++) {
        const int koff = kt * 32 + quad * 8;
        const int j    = kt * 4 + quad;
        bf16x8 ah[3], al[3], bh[4], bl[4];
#pragma unroll
        for (int mt = 0; mt < 3; mt++) {
            int row = (wave * 3 + mt) * 16 + m16;
            ah[mt] = *(const bf16x8*)(Wh + (size_t)row * KPAD + koff);
            al[mt] = *(const bf16x8*)(Wl + (size_t)row * KPAD + koff);
        }
#pragma unroll
        for (int nt = 0; nt < 4; nt++) {
            int u = (nt * 16 + m16) * NGB + j;
            bh[nt] = *(const bf16x8*)(xh + u * 8);
            bl[nt] = *(const bf16x8*)(xl + u * 8);
        }
#pragma unroll
        for (int mt = 0; mt < 3; mt++)
#pragma unroll
            for (int nt = 0; nt < 4; nt++) {
                acc[mt][nt] = __builtin_amdgcn_mfma_f32_16x16x32_bf16(ah[mt], bh[nt], acc[mt][nt], 0, 0, 0);
                acc[mt][nt] = __builtin_amdgcn_mfma_f32_16x16x32_bf16(al[mt], bh[nt], acc[mt][nt], 0, 0, 0);
                acc[mt][nt] = __builtin_amdgcn_mfma_f32_16x16x32_bf16(ah[mt], bl[nt], acc[mt][nt], 0, 0, 0);
            }
    }

    __syncthreads();
    float* tr = (float*)xh;
    const float bo = bias[wave];
#pragma unroll
    for (int nt = 0; nt < 4; nt++) {
        float s = 0.f;
#pragma unroll
        for (int mt = 0; mt < 3; mt++)
#pragma unroll
            for (int r = 0; r < 4; r++) s += softplus_f(acc[mt][nt][r] + bo);
        s += __shfl_xor(s, 16);
        s += __shfl_xor(s, 32);
        if (quad == 0) tr[(nt * 16 + m16) * 8 + wave] = s * (1.f / 48.f);
    }
    store_split8(tr, tid, (bS + s0) * 8, OutH, OutL);
}

// ---------------------------------------------------------------------------
// Layer 2 fused with vector-channel reduction. Same DMA staging; 8 waves =
// 4 nt x 2 kh (K halves); combine halves via LDS; softplus+bias+mean, dot
// with C, per-block partial.
// ---------------------------------------------------------------------------
__global__ __launch_bounds__(512) void layer2_fused(
    const __bf16* __restrict__ Ah, const __bf16* __restrict__ Al,
    const __bf16* __restrict__ Wh, const __bf16* __restrict__ Wl,
    const float* __restrict__ bias, const int* __restrict__ NN,
    const float* __restrict__ C, float* __restrict__ part)
{
    constexpr int CT = 64, KPAD = 128, NU = NGB * CT;
    __shared__ __align__(16) __bf16 xh[840 * 8];
    __shared__ __align__(16) __bf16 xl[840 * 8];
    __shared__ float wsum[4][3];

    const int tid  = threadIdx.x;
    const int wave = tid >> 6, lane = tid & 63;
    const int m16  = lane & 15, quad = lane >> 4;
    const int b    = blockIdx.x >> 6;
    const int s0   = (blockIdx.x & 63) << 6;
    const size_t bS = (size_t)b * SITES;

#pragma unroll
    for (int it = 0; it < 2; it++) {
        int u = tid + it * 512;
        if (u < NU) {
            int col = u / NGB, j = u - col * NGB;
            size_t g8 = (bS + NN[j * SITES + s0 + col]) * 8;
            gl_lds16(Ah + g8, xh + (size_t)u * 8);
            gl_lds16(Al + g8, xl + (size_t)u * 8);
        }
    }
    if (tid < 8) {
        bf16x8 z = {};
        *(bf16x8*)(xh + (NU + tid) * 8) = z;
        *(bf16x8*)(xl + (NU + tid) * 8) = z;
    }
    __syncthreads();

    const int nt = wave & 3, kh = wave >> 2;

    f32x4 acc[3];
#pragma unroll
    for (int mt = 0; mt < 3; mt++) acc[mt] = (f32x4){0.f, 0.f, 0.f, 0.f};

#pragma unroll
    for (int kk = 0; kk < 2; kk++) {
        const int kt   = kh * 2 + kk;
        const int koff = kt * 32 + quad * 8;
        const int j    = kt * 4 + quad;
        bf16x8 ah[3], al[3];
#pragma unroll
        for (int mt = 0; mt < 3; mt++) {
            int row = mt * 16 + m16;
            ah[mt] = *(const bf16x8*)(Wh + (size_t)row * KPAD + koff);
            al[mt] = *(const bf16x8*)(Wl + (size_t)row * KPAD + koff);
        }
        int u = (nt * 16 + m16) * NGB + j;
        bf16x8 bh = *(const bf16x8*)(xh + u * 8);
        bf16x8 bl = *(const bf16x8*)(xl + u * 8);
#pragma unroll
        for (int mt = 0; mt < 3; mt++) {
            acc[mt] = __builtin_amdgcn_mfma_f32_16x16x32_bf16(ah[mt], bh, acc[mt], 0, 0, 0);
            acc[mt] = __builtin_amdgcn_mfma_f32_16x16x32_bf16(al[mt], bh, acc[mt], 0, 0, 0);
            acc[mt] = __builtin_amdgcn_mfma_f32_16x16x32_bf16(ah[mt], bl, acc[mt], 0, 0, 0);
        }
    }
    __syncthreads();                       // all K-loop LDS reads done

    float* hpart = (float*)xh;             // [nt][48][16] f32 = 12 KB
    if (kh == 1) {
#pragma unroll
        for (int mt = 0; mt < 3; mt++)
#pragma unroll
            for (int r = 0; r < 4; r++)
                hpart[nt * 768 + (mt * 16 + quad * 4 + r) * 16 + m16] = acc[mt][r];
    }
    __syncthreads();

    const float bo = bias[0];
    if (kh == 0) {
        float s = 0.f;
#pragma unroll
        for (int mt = 0; mt < 3; mt++)
#pragma unroll
            for (int r = 0; r < 4; r++)
                s += softplus_f(acc[mt][r] + bo +
                                hpart[nt * 768 + (mt * 16 + quad * 4 + r) * 16 + m16]);
        s += __shfl_xor(s, 16);
        s += __shfl_xor(s, 32);
        float a2 = s * (1.f / 48.f);
        int site = s0 + nt * 16 + m16;
        float y0 = a2 * C[site];
        float y1 = a2 * C[SITES + site];
        float y2 = a2 * C[2 * SITES + site];
#pragma unroll
        for (int d = 1; d <= 8; d <<= 1) {
            y0 += __shfl_xor(y0, d);
            y1 += __shfl_xor(y1, d);
            y2 += __shfl_xor(y2, d);
        }
        if (lane == 0) { wsum[nt][0] = y0; wsum[nt][1] = y1; wsum[nt][2] = y2; }
    }
    __syncthreads();
    if (tid < 3)
        part[blockIdx.x * 3 + tid] =
            wsum[0][tid] + wsum[1][tid] + wsum[2][tid] + wsum[3][tid];
}

// out[b,d] = (1/S) * sum_{64 chunks} part[b,chunk,d]
__global__ __launch_bounds__(256) void reduce_b(
    const float* __restrict__ part, float* __restrict__ out)
{
    int t = threadIdx.x;
    if (t < BATCH * 3) {
        int b = t / 3, d = t - b * 3;
        float s = 0.f;
        for (int c = 0; c < 64; c++) s += part[(b * 64 + c) * 3 + d];
        out[t] = s * (1.f / (float)SITES);
    }
}

// ---------------------------------------------------------------------------
extern "C" void kernel_launch(void* const* d_in, const int* in_sizes, int n_in,
                              void* d_out, int out_size, void* d_ws, size_t ws_size,
                              hipStream_t stream)
{
    const float* InStates = (const float*)d_in[0];
    const float* Psi0     = (const float*)d_in[1];
    const float* bias0    = (const float*)d_in[2];
    const float* Psi1     = (const float*)d_in[3];
    const float* bias1    = (const float*)d_in[4];
    const float* Psi2     = (const float*)d_in[5];
    const float* bias2    = (const float*)d_in[6];
    const float* wtVC     = (const float*)d_in[7];
    const float* ShellW   = (const float*)d_in[8];
    const float* gdiags   = (const float*)d_in[9];
    const int*   GnnPerms = (const int*)d_in[10];
    const int*   NNSites  = (const int*)d_in[11];
    const int*   S2Sh     = (const int*)d_in[12];

    float*  ws   = (float*)d_ws;
    float*  Avc  = ws + OFF_AVC;
    __bf16* U    = (__bf16*)(ws + OFF_U);
    __bf16* Ah0  = (__bf16*)(ws + OFF_AH0);
    __bf16* Al0  = (__bf16*)(ws + OFF_AL0);
    __bf16* Ah1  = (__bf16*)(ws + OFF_AH1);
    __bf16* Al1  = (__bf16*)(ws + OFF_AL1);
    float*  C    = ws + OFF_C;
    float*  PART = ws + OFF_PART;

    float* out = (float*)d_out;      // (64,3) f32

    hipMemsetAsync(Avc, 0, 39 * sizeof(float), stream);
    hipMemsetAsync(C, 0, 3 * SITES * sizeof(float), stream);

    precompute_kernel<<<272, 256, 0, stream>>>(Psi0, Psi1, Psi2, wtVC, gdiags,
                                               GnnPerms, ws);
    precompute_C<<<208, 256, 0, stream>>>(NNSites, S2Sh, ShellW, Avc, C);

    layer0_mfma<<<BATCH * 64, 512, 0, stream>>>(
        InStates, U + UW0H, U + UW0L, bias0, NNSites, Ah0, Al0);
    layer1_mfma<<<BATCH * 64, 512, 0, stream>>>(
        Ah0, Al0, U + UW1H, U + UW1L, bias1, NNSites, Ah1, Al1);
    layer2_fused<<<BATCH * 64, 512, 0, stream>>>(
        Ah1, Al1, U + UW2H, U + UW2L, bias2, NNSites, C, PART);

    reduce_b<<<1, 256, 0, stream>>>(PART, out);
}